// Round 8
// baseline (63.584 us; speedup 1.0000x reference)
//
#include <hip/hip_runtime.h>
#include <math.h>

// LIFNeuronFDE: fractional-order LIF with Grunwald-Letnikov memory.
//   v^{k+1} = 2*(I_k - v^k) - sum_{j=0}^{k} c_{k+1-j} v^{(j)},  v^{(0)} = v0
//   spike_k = sigmoid(5*(v^{k+1} - 1))
// T=32, B=32, N=32768.  Linear-map form: v_{k+1} = b[k]*v0 + sum_j a[k][j] I_j.
//
// R7 lesson: per-phase re-conversion was CSE'd away (same SSA source), so
// fp64 temps stayed live cross-phase -> AGPR split, 2.2 waves/SIMD, same
// counters as R6. Fix: LAUNDER If[j] through asm("" : "+v") at each phase
// start -> new SSA value, conversions cannot be CSE'd across phases, fp64
// temps die at phase end. 4 phases x 8 rows: peak liveness ~114 regs ->
// __launch_bounds__(256,4) (128-VGPR cap, 4 waves/SIMD). Laundering is
// bitwise-neutral; fma order per accumulator unchanged (b[k]*v0 init, j
// ascending) -> output bit-identical (absmax margin thin: 0.0176/0.02).

#define T_STEPS 32
#define BN (32 * 32768)              // B*N = 1,048,576 elements
#define PAIRS (BN / 2)               // 524,288 float2 work items
#define PH 8                         // rows per phase

struct LinMap {
    double a[T_STEPS][T_STEPS];      // a[k][j]: coeff of I_j in v_{k+1} (j<=k)
    double b[T_STEPS];               // b[k]:    coeff of v0  in v_{k+1}
};

constexpr LinMap make_linmap() {
    double c[T_STEPS + 1] = {};
    c[0] = 1.0;
    for (int j = 1; j <= T_STEPS; ++j) c[j] = c[j - 1] * (1.0 - 1.5 / (double)j);

    double vc[T_STEPS + 1][T_STEPS + 1] = {};   // coeff of basis m in v_k
    vc[0][0] = 1.0;                              // m=0 -> v0, m=1+j -> I_j

    LinMap r{};
    for (int k = 0; k < T_STEPS; ++k) {
        for (int m = 0; m <= T_STEPS; ++m) {
            double acc = -2.0 * vc[k][m];
            for (int j = 0; j <= k; ++j) acc -= c[k + 1 - j] * vc[j][m];
            vc[k + 1][m] = acc;
        }
        vc[k + 1][1 + k] += 2.0;
        r.b[k] = vc[k + 1][0];
        for (int j = 0; j < T_STEPS; ++j) r.a[k][j] = vc[k + 1][1 + j];
    }
    return r;
}

constexpr LinMap CM = make_linmap();

// Zero-instruction SSA rewrite: compiler must treat If[j] as a fresh value,
// so fp64 converts from a previous phase cannot be reused (kills cross-phase
// CSE and the resulting whole-kernel fp64 liveness).
template<int J1>
__device__ __forceinline__ void launder(float2 (&If)[T_STEPS])
{
    #pragma unroll
    for (int j = 0; j < J1; ++j) {
        asm volatile("" : "+v"(If[j].x), "+v"(If[j].y));
    }
}

template<int K0, int KEND>
__device__ __forceinline__ void init_s(double (&sx)[T_STEPS], double (&sy)[T_STEPS],
                                       const double v0x, const double v0y)
{
    #pragma unroll
    for (int k = K0; k < KEND; ++k) { sx[k] = CM.b[k] * v0x; sy[k] = CM.b[k] * v0y; }
}

// Scatter for rows [K0,KEND): j = 0..KEND-1 template-literal; cvt If[j] once
// per phase; update s[k] for k in [max(j,K0),KEND); emit row j when complete.
template<int J, int K0, int KEND>
__device__ __forceinline__ void scatter_phase(const float2 (&If)[T_STEPS],
                                              double (&sx)[T_STEPS], double (&sy)[T_STEPS],
                                              float2* __restrict__ out2, const int idx)
{
    if constexpr (J < KEND) {
        const double Ix = (double)If[J].x;   // phase-local cvt (laundered src)
        const double Iy = (double)If[J].y;
        constexpr int kst = (J > K0) ? J : K0;
        #pragma unroll
        for (int k = kst; k < KEND; ++k) {   // ascending j per accumulator
            sx[k] = fma(CM.a[k][J], Ix, sx[k]);
            sy[k] = fma(CM.a[k][J], Iy, sy[k]);
        }
        if constexpr (J >= K0) {             // row J complete -> emit, s[J] dies
            const float ax = (float)(-5.0 * (sx[J] - 1.0));
            const float ay = (float)(-5.0 * (sy[J] - 1.0));
            out2[(size_t)J * PAIRS + idx] =
                make_float2(__builtin_amdgcn_rcpf(1.0f + __expf(ax)),
                            __builtin_amdgcn_rcpf(1.0f + __expf(ay)));
        }
        scatter_phase<J + 1, K0, KEND>(If, sx, sy, out2, idx);
    }
}

// One phase: launder inputs -> init accumulators -> scatter + emit.
template<int K0>
__device__ __forceinline__ void phase(float2 (&If)[T_STEPS],
                                      double (&sx)[T_STEPS], double (&sy)[T_STEPS],
                                      const double v0x, const double v0y,
                                      float2* __restrict__ out2, const int idx)
{
    constexpr int KEND = K0 + PH;
    launder<KEND>(If);
    init_s<K0, KEND>(sx, sy, v0x, v0y);
    scatter_phase<0, K0, KEND>(If, sx, sy, out2, idx);
}

__global__ __launch_bounds__(256, 4) void lif_fde_kernel(
    const float* __restrict__ I,
    const float* __restrict__ v0,
    float* __restrict__ out)
{
    const int idx = blockIdx.x * blockDim.x + threadIdx.x;   // [0, PAIRS)

    const float2* __restrict__ I2   = (const float2*)I;
    const float2* __restrict__ v02  = (const float2*)v0;
    float2* __restrict__       out2 = (float2*)out;

    // Stage all of I (fp32, exact) as 32 independent dwordx2 loads.
    float2 If[T_STEPS];
    #pragma unroll
    for (int k = 0; k < T_STEPS; ++k) {
        If[k] = I2[(size_t)k * PAIRS + idx];
    }

    const float2 v0f = v02[idx];
    const double v0x = (double)v0f.x;
    const double v0y = (double)v0f.y;

    double sx[T_STEPS], sy[T_STEPS];

    phase<0>(If, sx, sy, v0x, v0y, out2, idx);
    phase<8>(If, sx, sy, v0x, v0y, out2, idx);
    phase<16>(If, sx, sy, v0x, v0y, out2, idx);
    phase<24>(If, sx, sy, v0x, v0y, out2, idx);
}

extern "C" void kernel_launch(void* const* d_in, const int* in_sizes, int n_in,
                              void* d_out, int out_size, void* d_ws, size_t ws_size,
                              hipStream_t stream) {
    const float* I  = (const float*)d_in[0];   // (T, B, N) fp32
    const float* v0 = (const float*)d_in[1];   // (B, N) fp32
    float* out = (float*)d_out;                // (T, B, N) fp32

    dim3 block(256);
    dim3 grid(PAIRS / 256);                    // 2048 blocks, exact fit
    lif_fde_kernel<<<grid, block, 0, stream>>>(I, v0, out);
}

// Round 10
// 48.621 us; speedup vs baseline: 1.3077x; 1.3077x over previous
//
#include <hip/hip_runtime.h>
#include <math.h>

// LIFNeuronFDE: fractional-order LIF with Grunwald-Letnikov memory.
//   v^{k+1} = 2*(I_k - v^k) - sum_{j=0}^{k} c_{k+1-j} v^{(j)},  v^{(0)} = v0
//   spike_k = sigmoid(5*(v^{k+1} - 1))
// T=32, B=32, N=32768.  Linear-map form: v_{k+1} = b[k]*v0 + sum_j a[k][j] I_j.
//
// R1-R8 lesson: every structural variant (occupancy 28-64%) lands at
// 55-65us; best is R6 (float2 gather, 55.7us). No pipe saturated ->
// limiter is the memory SYSTEM: I(128MiB)+out(128MiB) overflows the 256MiB
// L3; the zero-reuse output stream evicts I (steady-state FETCH=67MB of
// re-fetched I + HBM read/write turnaround).
//
// R10 = R9 fixed: __builtin_nontemporal_store rejects HIP_vector_type;
// use native clang ext_vector float2 for the nt store (same
// global_store_dwordx2 nt). Otherwise identical to R6 -> bitwise-same
// output (absmax margin thin: 0.0176/0.02).

#define T_STEPS 32
#define BN (32 * 32768)              // B*N = 1,048,576 elements
#define PAIRS (BN / 2)               // 524,288 float2 work items

typedef float f32x2 __attribute__((ext_vector_type(2)));

struct LinMap {
    double a[T_STEPS][T_STEPS];      // a[k][j]: coeff of I_j in v_{k+1} (j<=k)
    double b[T_STEPS];               // b[k]:    coeff of v0  in v_{k+1}
};

constexpr LinMap make_linmap() {
    // GL coefficients: c_0=1, c_j = (1 - 1.5/j) c_{j-1}
    double c[T_STEPS + 1] = {};
    c[0] = 1.0;
    for (int j = 1; j <= T_STEPS; ++j) c[j] = c[j - 1] * (1.0 - 1.5 / (double)j);

    // vc[k][m]: coefficient of basis element m in v_k (m=0 -> v0, m=1+j -> I_j)
    double vc[T_STEPS + 1][T_STEPS + 1] = {};
    vc[0][0] = 1.0;

    LinMap r{};
    for (int k = 0; k < T_STEPS; ++k) {
        // v_{k+1} = 2*I_k - 2*v_k - sum_{j=0}^{k} c[k+1-j] * v_j
        for (int m = 0; m <= T_STEPS; ++m) {
            double acc = -2.0 * vc[k][m];
            for (int j = 0; j <= k; ++j) acc -= c[k + 1 - j] * vc[j][m];
            vc[k + 1][m] = acc;
        }
        vc[k + 1][1 + k] += 2.0;

        r.b[k] = vc[k + 1][0];
        for (int j = 0; j < T_STEPS; ++j) r.a[k][j] = vc[k + 1][1 + j];
    }
    return r;
}

constexpr LinMap CM = make_linmap();

// Row K: s = b[K]*v0 + sum_{j=0}^{K} a[K][j]*I_j (fp64, ascending j),
// then spike = sigmoid(5*(s-1)). All If[] indices are compile-time literals.
template<int K>
__device__ __forceinline__ void fde_rows(const float2 (&If)[T_STEPS],
                                         const double v0x, const double v0y,
                                         f32x2* __restrict__ out2,
                                         const int idx)
{
    if constexpr (K < T_STEPS) {
        double sx = CM.b[K] * v0x;
        double sy = CM.b[K] * v0y;
        #pragma unroll
        for (int j = 0; j <= K; ++j) {
            sx = fma(CM.a[K][j], (double)If[j].x, sx);
            sy = fma(CM.a[K][j], (double)If[j].y, sy);
        }
        const float ax = (float)(-5.0 * (sx - 1.0));
        const float ay = (float)(-5.0 * (sy - 1.0));
        f32x2 sp;
        sp.x = 1.0f / (1.0f + __expf(ax));
        sp.y = 1.0f / (1.0f + __expf(ay));
        // Non-temporal store: output has zero reuse; keep it out of L3 so
        // I stays resident across replays.
        __builtin_nontemporal_store(sp, &out2[(size_t)K * PAIRS + idx]);

        fde_rows<K + 1>(If, v0x, v0y, out2, idx);
    }
}

__global__ __launch_bounds__(256) void lif_fde_kernel(
    const float* __restrict__ I,
    const float* __restrict__ v0,
    float* __restrict__ out)
{
    const int idx = blockIdx.x * blockDim.x + threadIdx.x;   // [0, PAIRS)

    const float2* __restrict__ I2   = (const float2*)I;
    const float2* __restrict__ v02  = (const float2*)v0;
    f32x2* __restrict__        out2 = (f32x2*)out;

    // Stage all of I for this pair in fp32 registers (exact), issued as 32
    // independent dwordx2 loads -> one pipelined latency hit.
    float2 If[T_STEPS];
    #pragma unroll
    for (int k = 0; k < T_STEPS; ++k) {
        If[k] = I2[(size_t)k * PAIRS + idx];
    }

    const float2 v0f = v02[idx];
    const double v0x = (double)v0f.x;
    const double v0y = (double)v0f.y;

    fde_rows<0>(If, v0x, v0y, out2, idx);
}

extern "C" void kernel_launch(void* const* d_in, const int* in_sizes, int n_in,
                              void* d_out, int out_size, void* d_ws, size_t ws_size,
                              hipStream_t stream) {
    const float* I  = (const float*)d_in[0];   // (T, B, N) fp32
    const float* v0 = (const float*)d_in[1];   // (B, N) fp32
    float* out = (float*)d_out;                // (T, B, N) fp32

    dim3 block(256);
    dim3 grid(PAIRS / 256);                    // 2048 blocks, exact fit
    lif_fde_kernel<<<grid, block, 0, stream>>>(I, v0, out);
}